// Round 2
// baseline (4242.057 us; speedup 1.0000x reference)
//
#include <hip/hip_runtime.h>
#include <hip/hip_bf16.h>
#include <math.h>

using bf16 = __hip_bfloat16;

#define DEV static __device__ __forceinline__

constexpr int NENT = 40000;
constexpr int DIM  = 200;
constexpr int EE   = 80000;      // edges per side
constexpr int TOTE = 2 * EE;     // 160000
constexpr int BQ   = 1024;
constexpr int TE   = 64;         // edges per block tile
constexpr int NTS  = EE / TE;    // 1250 tiles per side
constexpr int KK   = 20;         // k-chunk for B staging
constexpr int LDA  = 204;        // padded LDS stride
constexpr float EPSBN = 1e-5f;
constexpr size_t XOFF = (size_t)2 * BQ * DIM;   // x-region element offset inside d_out

// "maybe-typed" pointer: bf16 or f32 decided at runtime by the detect flag
struct MP { const void* p; };

DEV float b2f(unsigned int u) { union { unsigned int i; float f; } v; v.i = u << 16; return v.f; }

DEV float ld(MP m, size_t i, int bf) {
  return bf ? b2f(((const unsigned short*)m.p)[i]) : ((const float*)m.p)[i];
}
DEV void ld8(MP m, size_t i, float* o, int bf) {
  if (bf) {
    uint4 u = *(const uint4*)((const unsigned short*)m.p + i);
    o[0]=b2f(u.x & 0xffffu); o[1]=b2f(u.x >> 16);
    o[2]=b2f(u.y & 0xffffu); o[3]=b2f(u.y >> 16);
    o[4]=b2f(u.z & 0xffffu); o[5]=b2f(u.z >> 16);
    o[6]=b2f(u.w & 0xffffu); o[7]=b2f(u.w >> 16);
  } else {
    const float4* q = (const float4*)((const float*)m.p + i);
    float4 a = q[0], b = q[1];
    o[0]=a.x; o[1]=a.y; o[2]=a.z; o[3]=a.w; o[4]=b.x; o[5]=b.y; o[6]=b.z; o[7]=b.w;
  }
}
DEV void f32load8(const float* p, float* o) {
  const float4* q = (const float4*)p;
  float4 a = q[0], b = q[1];
  o[0]=a.x; o[1]=a.y; o[2]=a.z; o[3]=a.w; o[4]=b.x; o[5]=b.y; o[6]=b.z; o[7]=b.w;
}
DEV void st(void* p, size_t i, float v, int bf) {
  if (bf) ((bf16*)p)[i] = __float2bfloat16(v);
  else    ((float*)p)[i] = v;
}

// ---------------- dtype detect ----------------
// Reads first 2048 uint16s of init_embed. True-bf16 N(0,0.05^2) data has sane
// exponents; f32 data read as bf16 pairs has ~50% absurd exponents (low halves).
__global__ void detect_kernel(const unsigned short* __restrict__ e, int* __restrict__ flag) {
  int tid = threadIdx.x;
  int absurd = 0;
  for (int i = tid; i < 2048; i += 64) {
    int ex = (e[i] >> 7) & 0xFF;
    if (ex >= 0xD0 || (ex != 0 && ex <= 0x50)) absurd++;
  }
  for (int o = 32; o; o >>= 1) absurd += __shfl_down(absurd, o);
  if (tid == 0) *flag = (absurd > 64) ? 0 : 1;   // 1 => bf16 world
}

// ---------------- small kernels ----------------
__global__ void deg_hist_kernel(const int* __restrict__ ei,
                                float* __restrict__ deg_in, float* __restrict__ deg_out) {
  int i = blockIdx.x * 256 + threadIdx.x;
  if (i >= TOTE) return;
  int s = ei[i];
  atomicAdd((i < EE ? deg_in : deg_out) + s, 1.0f);
}

__global__ void norm_kernel(const int* __restrict__ ei,
                            const float* __restrict__ deg_in, const float* __restrict__ deg_out,
                            float* __restrict__ norm_in, float* __restrict__ norm_out) {
  int i = blockIdx.x * 256 + threadIdx.x;
  if (i >= TOTE) return;
  int s = ei[i], d = ei[TOTE + i];
  const float* deg = (i < EE) ? deg_in : deg_out;
  float a = deg[s], b = deg[d];
  float na = a > 0.f ? rsqrtf(a) : 0.f;
  float nb = b > 0.f ? rsqrtf(b) : 0.f;
  if (i < EE) norm_in[i] = na * nb; else norm_out[i - EE] = na * nb;
}

__global__ void copy_f32_kernel(MP s, float* __restrict__ d, int n, const int* __restrict__ flagp) {
  int bf = *flagp;
  int i = blockIdx.x * 256 + threadIdx.x;
  if (i < n) d[i] = ld(s, i, bf);
}

// wp[d,f] = loop_rel[d] * w_loop[d,f]
__global__ void wprime_kernel(MP w, MP lr, float* __restrict__ wp, const int* __restrict__ flagp) {
  int bf = *flagp;
  int i = blockIdx.x * 256 + threadIdx.x;
  if (i < DIM * DIM) wp[i] = ld(w, i, bf) * ld(lr, i / DIM, bf);
}

// tiny [200,200]@[200,200] GEMM (rel chain). a_use_flag: A maybe-typed (1) or f32 (0). B always maybe-typed.
__global__ void mat200_kernel(MP A, int a_use_flag, MP B, float* __restrict__ C,
                              const int* __restrict__ flagp) {
  int bf = *flagp;
  int abf = a_use_flag ? bf : 0;
  int i = blockIdx.x, c = threadIdx.x;
  if (c >= DIM) return;
  float acc = 0.f;
  for (int d = 0; d < DIM; ++d)
    acc = fmaf(ld(A, (size_t)i * DIM + d, abf), ld(B, (size_t)d * DIM + c, bf), acc);
  C[(size_t)i * DIM + c] = acc;
}

// ---------------- shared GEMM tile: [64,200] (LDS) @ [200,200] (global) ----------------
DEV void gemm_tile(float (*As)[LDA], float (*Bs)[DIM], MP B, int bfb,
                   int r0, int c0, float* acc0, float* acc1, int tid) {
  for (int kk = 0; kk < DIM; kk += KK) {
    __syncthreads();                       // protect Bs from previous chunk's readers
    for (int i = tid; i < KK * DIM / 8; i += 256) {
      float t[8];
      ld8(B, (size_t)kk * DIM + i * 8, t, bfb);
      float4* d = (float4*)(&Bs[0][0] + i * 8);
      d[0] = make_float4(t[0], t[1], t[2], t[3]);
      d[1] = make_float4(t[4], t[5], t[6], t[7]);
    }
    __syncthreads();
#pragma unroll
    for (int k = 0; k < KK; ++k) {
      float a0 = As[r0][kk + k], a1 = As[r0 + 1][kk + k];
#pragma unroll
      for (int j = 0; j < 25; ++j) {
        float b = Bs[k][c0 + j];
        acc0[j] = fmaf(a0, b, acc0[j]);
        acc1[j] = fmaf(a1, b, acc1[j]);
      }
    }
  }
  __syncthreads();                         // all As reads done -> caller may overwrite As
}

// ---------------- loop (self-edge) GEMM: agg = x @ wp  (wp is f32) ----------------
__global__ __launch_bounds__(256, 2) void loop_gemm_kernel(MP x, size_t xoff,
                                                           const float* __restrict__ wp,
                                                           float* __restrict__ agg,
                                                           const int* __restrict__ flagp) {
  __shared__ float As[TE][LDA];
  __shared__ float Bs[KK][DIM];
  const int bf = *flagp;
  const int tid = threadIdx.x;
  const int m0 = blockIdx.x * TE;
  for (int i = tid; i < TE * (DIM / 8); i += 256) {
    int r = i / (DIM / 8), c8 = i - r * (DIM / 8);
    float o[8];
    ld8(x, xoff + (size_t)(m0 + r) * DIM + c8 * 8, o, bf);
    float4* d = (float4*)&As[r][c8 * 8];
    d[0] = make_float4(o[0], o[1], o[2], o[3]);
    d[1] = make_float4(o[4], o[5], o[6], o[7]);
  }
  const int rg = tid >> 3, cg = tid & 7;
  const int r0 = rg * 2, c0 = cg * 25;
  float acc0[25], acc1[25];
#pragma unroll
  for (int j = 0; j < 25; ++j) { acc0[j] = 0.f; acc1[j] = 0.f; }
  MP wpm; wpm.p = wp;
  gemm_tile(As, Bs, wpm, 0, r0, c0, acc0, acc1, tid);
  float* o0 = agg + (size_t)(m0 + r0) * DIM + c0;
  float* o1 = agg + (size_t)(m0 + r0 + 1) * DIM + c0;
#pragma unroll
  for (int j = 0; j < 25; ++j) { o0[j] = acc0[j]; o1[j] = acc1[j]; }
}

// ---------------- fused edge kernel (both sides) ----------------
__global__ __launch_bounds__(256, 2) void edge_kernel(
    MP x, size_t xoff, const float* __restrict__ re,
    const int* __restrict__ ei, const int* __restrict__ ety,
    const int* __restrict__ qe, const int* __restrict__ qr,
    const float* __restrict__ norm_in, const float* __restrict__ norm_out,
    MP w_q, MP w_in, MP w_out,
    float* __restrict__ agg, const int* __restrict__ flagp) {
  __shared__ float As[TE][LDA];
  __shared__ float Bs[KK][DIM];
  __shared__ int s_src[TE], s_dst[TE], s_et[TE];
  __shared__ int s_qe0[TE], s_qe1[TE], s_qr0[TE], s_qr1[TE];
  __shared__ float s_norm[TE];

  const int bf = *flagp;
  const int tid = threadIdx.x;
  const int blk = blockIdx.x;
  const int side = blk >= NTS ? 1 : 0;
  const int tile = blk - side * NTS;
  const int eb = tile * TE;
  const int gb = side * EE + eb;

  if (tid < TE) {
    int ge = gb + tid;
    s_src[tid] = ei[ge];
    s_dst[tid] = ei[TOTE + ge];
    s_et[tid]  = ety[ge];
    s_qe0[tid] = qe[ge];
    s_qe1[tid] = qe[TOTE + ge];
    s_qr0[tid] = qr[ge];
    s_qr1[tid] = qr[TOTE + ge];
    s_norm[tid] = side ? norm_out[eb + tid] : norm_in[eb + tid];
  }
  __syncthreads();

  // stage t1 = sum_q x[qe]*re[qr] into As
  for (int i = tid; i < TE * (DIM / 8); i += 256) {
    int r = i / (DIM / 8), c8 = i - r * (DIM / 8);
    float xa[8], ra[8], xb[8], rb[8], o[8];
    ld8(x, xoff + (size_t)s_qe0[r] * DIM + c8 * 8, xa, bf);
    f32load8(re + (size_t)s_qr0[r] * DIM + c8 * 8, ra);
    ld8(x, xoff + (size_t)s_qe1[r] * DIM + c8 * 8, xb, bf);
    f32load8(re + (size_t)s_qr1[r] * DIM + c8 * 8, rb);
#pragma unroll
    for (int j = 0; j < 8; ++j) o[j] = xa[j] * ra[j] + xb[j] * rb[j];
    float4* d = (float4*)&As[r][c8 * 8];
    d[0] = make_float4(o[0], o[1], o[2], o[3]);
    d[1] = make_float4(o[4], o[5], o[6], o[7]);
  }

  const int rg = tid >> 3, cg = tid & 7;
  const int r0 = rg * 2, c0 = cg * 25;
  float acc0[25], acc1[25];
#pragma unroll
  for (int j = 0; j < 25; ++j) { acc0[j] = 0.f; acc1[j] = 0.f; }

  gemm_tile(As, Bs, w_q, bf, r0, c0, acc0, acc1, tid);   // qual = t1 @ w_q

  // rel_e = 0.5*(re[etype] + qual); m = x[src] * rel_e -> back into As
  {
    const size_t e0 = (size_t)s_et[r0] * DIM, e1 = (size_t)s_et[r0 + 1] * DIM;
    const size_t sx0 = xoff + (size_t)s_src[r0] * DIM, sx1 = xoff + (size_t)s_src[r0 + 1] * DIM;
#pragma unroll
    for (int j = 0; j < 25; ++j) {
      int c = c0 + j;
      float q0 = 0.5f * (re[e0 + c] + acc0[j]);
      float q1 = 0.5f * (re[e1 + c] + acc1[j]);
      As[r0][c]     = ld(x, sx0 + c, bf) * q0;
      As[r0 + 1][c] = ld(x, sx1 + c, bf) * q1;
      acc0[j] = 0.f; acc1[j] = 0.f;
    }
  }
  // (gemm_tile's internal barriers order the As writes above before any As reads)

  gemm_tile(As, Bs, side ? w_out : w_in, bf, r0, c0, acc0, acc1, tid);  // msg = m @ W

  {
    const float n0 = s_norm[r0], n1 = s_norm[r0 + 1];
    float* a0p = agg + (size_t)s_dst[r0] * DIM + c0;
    float* a1p = agg + (size_t)s_dst[r0 + 1] * DIM + c0;
#pragma unroll
    for (int j = 0; j < 25; ++j) {
      atomicAdd(a0p + j, acc0[j] * n0);
      atomicAdd(a1p + j, acc1[j] * n1);
    }
  }
}

// ---------------- BatchNorm ----------------
// (reference's +bias is a per-column constant: cancels exactly in BN -> skipped)
__global__ __launch_bounds__(256) void bn_reduce_kernel(const float* __restrict__ agg,
                                                        float* __restrict__ sums) {
  int tid = threadIdx.x;
  if (tid >= DIM) return;
  int row0 = blockIdx.x * 160;
  float s = 0.f, s2 = 0.f;
  for (int r = row0; r < row0 + 160; ++r) {
    float v = agg[(size_t)r * DIM + tid] * (1.f / 3.f);
    s += v; s2 += v * v;
  }
  atomicAdd(&sums[tid], s);
  atomicAdd(&sums[DIM + tid], s2);
}

__global__ __launch_bounds__(256) void bn_apply_kernel(const float* __restrict__ agg,
                                                       const float* __restrict__ sums,
                                                       MP gamma, MP beta,
                                                       void* __restrict__ xout, size_t ooff,
                                                       const int* __restrict__ flagp) {
  __shared__ float sc[DIM], sh[DIM];
  const int bf = *flagp;
  int tid = threadIdx.x;
  if (tid < DIM) {
    float mean = sums[tid] * (1.f / NENT);
    float var  = sums[DIM + tid] * (1.f / NENT) - mean * mean;
    float s = ld(gamma, tid, bf) * rsqrtf(var + EPSBN);
    sc[tid] = s;
    sh[tid] = ld(beta, tid, bf) - mean * s;
  }
  __syncthreads();
  int stride = gridDim.x * blockDim.x;
  for (int i = blockIdx.x * blockDim.x + tid; i < NENT * DIM; i += stride) {
    int c = i % DIM;
    float v = agg[i] * (1.f / 3.f);
    st(xout, ooff + i, tanhf(fmaf(v, sc[c], sh[c])), bf);
  }
}

// ---------------- output gathers ----------------
__global__ void gather_kernel(void* __restrict__ out, const float* __restrict__ rfin,
                              const int* __restrict__ sub, const int* __restrict__ rel,
                              const int* __restrict__ flagp) {
  const int bf = *flagp;
  int i = blockIdx.x * 256 + threadIdx.x;
  MP xm; xm.p = out;
  if (i < BQ * DIM) {
    int b = i / DIM, c = i - b * DIM;
    st(out, i, ld(xm, XOFF + (size_t)sub[b] * DIM + c, bf), bf);
  } else if (i < 2 * BQ * DIM) {
    int j = i - BQ * DIM;
    int b = j / DIM, c = j - b * DIM;
    st(out, i, rfin[(size_t)rel[b] * DIM + c], bf);
  }
}

// ---------------- launch ----------------
extern "C" void kernel_launch(void* const* d_in, const int* in_sizes, int n_in,
                              void* d_out, int out_size, void* d_ws, size_t ws_size,
                              hipStream_t stream) {
  (void)in_sizes; (void)n_in; (void)out_size; (void)ws_size;
  const int* ei  = (const int*)d_in[0];
  const int* ety = (const int*)d_in[1];
  const int* qe  = (const int*)d_in[2];
  const int* qr  = (const int*)d_in[3];
  const int* sub = (const int*)d_in[4];
  const int* rel = (const int*)d_in[5];
  MP x0     = { d_in[6] };
  MP ir     = { d_in[7] };
  MP w_loop[2] = { { d_in[8] },  { d_in[17] } };
  MP w_in[2]   = { { d_in[9] },  { d_in[18] } };
  MP w_out[2]  = { { d_in[10] }, { d_in[19] } };
  MP w_rel[2]  = { { d_in[11] }, { d_in[20] } };
  MP w_q[2]    = { { d_in[12] }, { d_in[21] } };
  MP lr[2]     = { { d_in[13] }, { d_in[22] } };
  // bias (d_in[14]/d_in[23]) cancels exactly in BatchNorm -> unused
  MP gamma[2]  = { { d_in[15] }, { d_in[24] } };
  MP beta[2]   = { { d_in[16] }, { d_in[25] } };

  float* ws = (float*)d_ws;
  float* deg_in   = ws;                        // 40000
  float* deg_out  = ws + 40000;                // 40000
  float* sums1    = ws + 80000;                // 400
  float* sums2    = ws + 80400;                // 400
  int*   flag     = (int*)(ws + 80800);        // 16
  float* norm_in  = ws + 80816;                // 80000
  float* norm_out = ws + 160816;               // 80000
  float* rel1     = ws + 240816;               // [200,200] f32
  float* rel2     = ws + 280816;               // [200,200]
  float* rfin     = ws + 320816;               // [200,200]
  float* wp1      = ws + 360816;               // [200,200]
  float* wp2      = ws + 400816;               // [200,200]
  float* agg      = ws + 440816;               // [NENT, DIM] f32
  // total ws use: 8,440,816 floats = 32.2 MiB (x1 lives in d_out's x-region)

  hipMemsetAsync(ws, 0, 80800 * sizeof(float), stream);  // deg + sums

  detect_kernel<<<1, 64, 0, stream>>>((const unsigned short*)d_in[6], flag);
  deg_hist_kernel<<<(TOTE + 255) / 256, 256, 0, stream>>>(ei, deg_in, deg_out);
  norm_kernel<<<(TOTE + 255) / 256, 256, 0, stream>>>(ei, deg_in, deg_out, norm_in, norm_out);
  copy_f32_kernel<<<(DIM * DIM + 255) / 256, 256, 0, stream>>>(ir, rel1, DIM * DIM, flag);
  mat200_kernel<<<DIM, 256, 0, stream>>>(ir, 1, w_rel[0], rel2, flag);
  MP rel2m = { rel2 };
  mat200_kernel<<<DIM, 256, 0, stream>>>(rel2m, 0, w_rel[1], rfin, flag);
  wprime_kernel<<<(DIM * DIM + 255) / 256, 256, 0, stream>>>(w_loop[0], lr[0], wp1, flag);
  wprime_kernel<<<(DIM * DIM + 255) / 256, 256, 0, stream>>>(w_loop[1], lr[1], wp2, flag);

  // ---- layer 1 (x = init_embed) ----
  loop_gemm_kernel<<<NENT / TE, 256, 0, stream>>>(x0, 0, wp1, agg, flag);
  edge_kernel<<<2 * NTS, 256, 0, stream>>>(x0, 0, rel1, ei, ety, qe, qr, norm_in, norm_out,
                                           w_q[0], w_in[0], w_out[0], agg, flag);
  bn_reduce_kernel<<<NENT / 160, 256, 0, stream>>>(agg, sums1);
  // x1 stored (world dtype) into d_out's x-region
  bn_apply_kernel<<<2048, 256, 0, stream>>>(agg, sums1, gamma[0], beta[0], d_out, XOFF, flag);

  // ---- layer 2 (x = x1 in d_out x-region) ----
  MP x1 = { d_out };
  loop_gemm_kernel<<<NENT / TE, 256, 0, stream>>>(x1, XOFF, wp2, agg, flag);
  edge_kernel<<<2 * NTS, 256, 0, stream>>>(x1, XOFF, rel2, ei, ety, qe, qr, norm_in, norm_out,
                                           w_q[1], w_in[1], w_out[1], agg, flag);
  bn_reduce_kernel<<<NENT / 160, 256, 0, stream>>>(agg, sums2);
  bn_apply_kernel<<<2048, 256, 0, stream>>>(agg, sums2, gamma[1], beta[1], d_out, XOFF, flag);

  gather_kernel<<<(2 * BQ * DIM + 255) / 256, 256, 0, stream>>>(d_out, rfin, sub, rel, flag);
}

// Round 3
// 1070.874 us; speedup vs baseline: 3.9613x; 3.9613x over previous
//
#include <hip/hip_runtime.h>
#include <hip/hip_bf16.h>
#include <math.h>

using bf16 = __hip_bfloat16;

#define DEV static __device__ __forceinline__

constexpr int NENT = 40000;
constexpr int DIM  = 200;
constexpr int EE   = 80000;      // edges per side
constexpr int TOTE = 2 * EE;     // 160000
constexpr int BQ   = 1024;
constexpr float EPSBN = 1e-5f;
constexpr size_t XOFF = (size_t)2 * BQ * DIM;   // x-region element offset inside d_out

// MFMA GEMM geometry: block tile M=128, N=208 (13x16), K padded to 224 (7x32)
constexpr int KP   = 224;
constexpr int NP   = 208;
constexpr int LDAS = 232;        // LDS A stride (ushorts): 464B rows -> conflict-free rotation
constexpr int MT_EDGE = TOTE / 128;   // 1250 m-tiles for edge GEMMs
constexpr int MT_SIDE = EE / 128;     // 625 (side boundary)
constexpr int MT_LOOP = (NENT + 127) / 128;  // 313

typedef __attribute__((ext_vector_type(8))) short s8v;   // 8 x bf16 (4 VGPRs)
typedef __attribute__((ext_vector_type(4))) float f4v;   // MFMA accumulator

struct MP { const void* p; };    // world-dtype (bf16|f32) pointer, runtime flag

DEV float b2f(unsigned int u) { union { unsigned int i; float f; } v; v.i = u << 16; return v.f; }

DEV float ld(MP m, size_t i, int bf) {
  return bf ? b2f(((const unsigned short*)m.p)[i]) : ((const float*)m.p)[i];
}
DEV void ld8(MP m, size_t i, float* o, int bf) {
  if (bf) {
    uint4 u = *(const uint4*)((const unsigned short*)m.p + i);
    o[0]=b2f(u.x & 0xffffu); o[1]=b2f(u.x >> 16);
    o[2]=b2f(u.y & 0xffffu); o[3]=b2f(u.y >> 16);
    o[4]=b2f(u.z & 0xffffu); o[5]=b2f(u.z >> 16);
    o[6]=b2f(u.w & 0xffffu); o[7]=b2f(u.w >> 16);
  } else {
    const float4* q = (const float4*)((const float*)m.p + i);
    float4 a = q[0], b = q[1];
    o[0]=a.x; o[1]=a.y; o[2]=a.z; o[3]=a.w; o[4]=b.x; o[5]=b.y; o[6]=b.z; o[7]=b.w;
  }
}
DEV void f32load8(const float* p, float* o) {
  const float4* q = (const float4*)p;
  float4 a = q[0], b = q[1];
  o[0]=a.x; o[1]=a.y; o[2]=a.z; o[3]=a.w; o[4]=b.x; o[5]=b.y; o[6]=b.z; o[7]=b.w;
}
DEV void st(void* p, size_t i, float v, int bf) {
  if (bf) ((bf16*)p)[i] = __float2bfloat16(v);
  else    ((float*)p)[i] = v;
}
DEV unsigned short f2b(float f) {   // RNE f32 -> bf16 bits (inputs never NaN)
  union { float f; unsigned int i; } v; v.f = f;
  return (unsigned short)((v.i + 0x7fffu + ((v.i >> 16) & 1u)) >> 16);
}
DEV uint4 pack8(const float* o) {
  uint4 u;
  u.x = (unsigned)f2b(o[0]) | ((unsigned)f2b(o[1]) << 16);
  u.y = (unsigned)f2b(o[2]) | ((unsigned)f2b(o[3]) << 16);
  u.z = (unsigned)f2b(o[4]) | ((unsigned)f2b(o[5]) << 16);
  u.w = (unsigned)f2b(o[6]) | ((unsigned)f2b(o[7]) << 16);
  return u;
}

// ---------------- dtype detect ----------------
__global__ void detect_kernel(const unsigned short* __restrict__ e, int* __restrict__ flag) {
  int tid = threadIdx.x;
  int absurd = 0;
  for (int i = tid; i < 2048; i += 64) {
    int ex = (e[i] >> 7) & 0xFF;
    if (ex >= 0xD0 || (ex != 0 && ex <= 0x50)) absurd++;
  }
  for (int o = 32; o; o >>= 1) absurd += __shfl_down(absurd, o);
  if (tid == 0) *flag = (absurd > 64) ? 0 : 1;   // 1 => bf16 world
}

// ---------------- small kernels ----------------
__global__ void deg_hist_kernel(const int* __restrict__ ei,
                                float* __restrict__ deg_in, float* __restrict__ deg_out) {
  int i = blockIdx.x * 256 + threadIdx.x;
  if (i >= TOTE) return;
  atomicAdd((i < EE ? deg_in : deg_out) + ei[i], 1.0f);
}

__global__ void norm_kernel(const int* __restrict__ ei,
                            const float* __restrict__ deg_in, const float* __restrict__ deg_out,
                            float* __restrict__ normA) {
  int i = blockIdx.x * 256 + threadIdx.x;
  if (i >= TOTE) return;
  int s = ei[i], d = ei[TOTE + i];
  const float* deg = (i < EE) ? deg_in : deg_out;
  float a = deg[s], b = deg[d];
  float na = a > 0.f ? rsqrtf(a) : 0.f;
  float nb = b > 0.f ? rsqrtf(b) : 0.f;
  normA[i] = na * nb;
}

__global__ void copy_f32_kernel(MP s, float* __restrict__ d, int n, const int* __restrict__ flagp) {
  int bf = *flagp;
  int i = blockIdx.x * 256 + threadIdx.x;
  if (i < n) d[i] = ld(s, i, bf);
}

__global__ void wprime_kernel(MP w, MP lr, float* __restrict__ wp, const int* __restrict__ flagp) {
  int bf = *flagp;
  int i = blockIdx.x * 256 + threadIdx.x;
  if (i < DIM * DIM) wp[i] = ld(w, i, bf) * ld(lr, i / DIM, bf);
}

__global__ void mat200_kernel(MP A, int a_use_flag, MP B, float* __restrict__ C,
                              const int* __restrict__ flagp) {
  int bf = *flagp;
  int abf = a_use_flag ? bf : 0;
  int i = blockIdx.x, c = threadIdx.x;
  if (c >= DIM) return;
  float acc = 0.f;
  for (int d = 0; d < DIM; ++d)
    acc = fmaf(ld(A, (size_t)i * DIM + d, abf), ld(B, (size_t)d * DIM + c, bf), acc);
  C[(size_t)i * DIM + c] = acc;
}

// Bt[n][k] = W^T padded to [208][224] bf16, optionally folding loop_rel: W'[k][n]=lr[k]*W[k][n]
__global__ void btprep_kernel(MP w, MP lrp, int has_lr, unsigned short* __restrict__ bt,
                              const int* __restrict__ flagp) {
  int bf = *flagp;
  int n = blockIdx.x, k = threadIdx.x;
  if (k >= KP) return;
  float v = 0.f;
  if (n < DIM && k < DIM) {
    v = ld(w, (size_t)k * DIM + n, bf);
    if (has_lr) v *= ld(lrp, k, bf);
  }
  bt[(size_t)n * KP + k] = f2b(v);
}

// ---------------- MFMA GEMM (fast path) ----------------
// EPI 0: loop  — A = x rows (world), B = wp^T, store agg[m] = C
// EPI 1: qual  — A = t1 built in staging (gathers), B = w_q^T, epilogue builds mbf
// EPI 2: msg   — A = mbf, B = w_in^T / w_out^T by side, epilogue atomicAdd agg[dst] += C*norm
template<int EPI>
__global__ __launch_bounds__(256, 2) void mfma_gemm(
    const unsigned short* __restrict__ Abf,
    MP x, size_t xoff,
    const float* __restrict__ re,
    const int* __restrict__ ei, const int* __restrict__ ety,
    const int* __restrict__ qe, const int* __restrict__ qr,
    const float* __restrict__ normA,
    const unsigned short* __restrict__ Bt0, const unsigned short* __restrict__ Bt1,
    float* __restrict__ agg,
    unsigned short* __restrict__ mbf,
    const int* __restrict__ flagp) {
  __shared__ unsigned short As[128][LDAS];
  __shared__ int  sIdx[128 * 4];
  __shared__ int  sA[128], sB[128];
  __shared__ float sN[128];

  const int bf  = *flagp;
  const int tid = threadIdx.x;
  const int m0  = blockIdx.x * 128;

  // ---- index staging ----
  if (EPI == 1 && tid < 128) {
    int e = m0 + tid;
    sIdx[tid]       = qe[e];
    sIdx[128 + tid] = qe[TOTE + e];
    sIdx[256 + tid] = qr[e];
    sIdx[384 + tid] = qr[TOTE + e];
    sA[tid] = ei[e];        // src
    sB[tid] = ety[e];
  }
  if (EPI == 2 && tid < 128) {
    int e = m0 + tid;
    sA[tid] = ei[TOTE + e]; // dst
    sN[tid] = normA[e];
  }
  if (EPI == 1 || EPI == 2) __syncthreads();

  // ---- A-tile staging (128 x 224 bf16) ----
  for (int i = tid; i < 128 * 28; i += 256) {
    int r = i / 28, cg = i - r * 28;
    if (EPI == 2) {
      *(uint4*)&As[r][cg * 8] = *(const uint4*)(Abf + (size_t)(m0 + r) * KP + cg * 8);
    } else if (EPI == 1) {
      float o[8] = {0,0,0,0,0,0,0,0};
      if (cg < 25) {
        float xa[8], ra[8], xb[8], rb[8];
        ld8(x, xoff + (size_t)sIdx[r] * DIM + cg * 8, xa, bf);
        f32load8(re + (size_t)sIdx[256 + r] * DIM + cg * 8, ra);
        ld8(x, xoff + (size_t)sIdx[128 + r] * DIM + cg * 8, xb, bf);
        f32load8(re + (size_t)sIdx[384 + r] * DIM + cg * 8, rb);
#pragma unroll
        for (int j = 0; j < 8; ++j) o[j] = xa[j] * ra[j] + xb[j] * rb[j];
      }
      *(uint4*)&As[r][cg * 8] = pack8(o);
    } else {
      float o[8] = {0,0,0,0,0,0,0,0};
      int row = m0 + r;
      if (row < NENT && cg < 25) ld8(x, xoff + (size_t)row * DIM + cg * 8, o, bf);
      *(uint4*)&As[r][cg * 8] = pack8(o);
    }
  }
  __syncthreads();

  // ---- main MFMA loop ----
  const int lane = tid & 63;
  const int w    = tid >> 6;
  const int col  = lane & 15;
  const int quad = lane >> 4;
  const unsigned short* Bt = (EPI == 2 && blockIdx.x >= MT_SIDE) ? Bt1 : Bt0;
  const unsigned short* btl = Bt + (size_t)col * KP + quad * 8;

  f4v acc[26];
#pragma unroll
  for (int t = 0; t < 26; ++t) acc[t] = (f4v){0.f, 0.f, 0.f, 0.f};

  const int rbase = w * 32;
#pragma unroll
  for (int kc = 0; kc < 7; ++kc) {
    const int k0 = kc * 32;
    s8v a0 = __builtin_bit_cast(s8v, *(const uint4*)&As[rbase + col][k0 + quad * 8]);
    s8v a1 = __builtin_bit_cast(s8v, *(const uint4*)&As[rbase + 16 + col][k0 + quad * 8]);
#pragma unroll
    for (int nt = 0; nt < 13; ++nt) {
      s8v b = __builtin_bit_cast(s8v, *(const uint4*)(btl + (size_t)nt * 16 * KP + k0));
      acc[nt]      = __builtin_amdgcn_mfma_f32_16x16x32_bf16(a0, b, acc[nt], 0, 0, 0);
      acc[13 + nt] = __builtin_amdgcn_mfma_f32_16x16x32_bf16(a1, b, acc[13 + nt], 0, 0, 0);
    }
  }

  // ---- epilogue ----
#pragma unroll
  for (int mt = 0; mt < 2; ++mt) {
#pragma unroll
    for (int i = 0; i < 4; ++i) {
      const int lrow = rbase + mt * 16 + quad * 4 + i;
      const int grow = m0 + lrow;
      if (EPI == 0) {
        if (grow < NENT) {
          float* ap = agg + (size_t)grow * DIM;
#pragma unroll
          for (int nt = 0; nt < 13; ++nt) {
            int n = nt * 16 + col;
            if (n < DIM) ap[n] = acc[mt * 13 + nt][i];
          }
        }
      } else if (EPI == 1) {
        const int srcr = sA[lrow], etyr = sB[lrow];
        const float* rerow = re + (size_t)etyr * DIM;
        const size_t xrow = xoff + (size_t)srcr * DIM;
        unsigned short* mrow = mbf + (size_t)grow * KP;
#pragma unroll
        for (int nt = 0; nt < 13; ++nt) {
          int n = nt * 16 + col;
          float v = 0.f;
          if (n < DIM) {
            float relv = 0.5f * (rerow[n] + acc[mt * 13 + nt][i]);
            v = ld(x, xrow + n, bf) * relv;
          }
          if (n < NP) mrow[n] = f2b(v);
        }
        mrow[NP + col] = 0;    // zero k-pad cols 208..223
      } else {
        const int dstr = sA[lrow];
        const float nv = sN[lrow];
        float* ap = agg + (size_t)dstr * DIM;
#pragma unroll
        for (int nt = 0; nt < 13; ++nt) {
          int n = nt * 16 + col;
          if (n < DIM) atomicAdd(ap + n, acc[mt * 13 + nt][i] * nv);
        }
      }
    }
  }
}

// ---------------- fallback (round-2 proven path) ----------------
constexpr int TE = 64, NTS = EE / TE, KK = 20, LDA = 204;

DEV void gemm_tile(float (*As)[LDA], float (*Bs)[DIM], MP B, int bfb,
                   int r0, int c0, float* acc0, float* acc1, int tid) {
  for (int kk = 0; kk < DIM; kk += KK) {
    __syncthreads();
    for (int i = tid; i < KK * DIM / 8; i += 256) {
      float t[8];
      ld8(B, (size_t)kk * DIM + i * 8, t, bfb);
      float4* d = (float4*)(&Bs[0][0] + i * 8);
      d[0] = make_float4(t[0], t[1], t[2], t[3]);
      d[1] = make_float4(t[4], t[5], t[6], t[7]);
    }
    __syncthreads();
#pragma unroll
    for (int k = 0; k < KK; ++k) {
      float a0 = As[r0][kk + k], a1 = As[r0 + 1][kk + k];
#pragma unroll
      for (int j = 0; j < 25; ++j) {
        float b = Bs[k][c0 + j];
        acc0[j] = fmaf(a0, b, acc0[j]);
        acc1[j] = fmaf(a1, b, acc1[j]);
      }
    }
  }
  __syncthreads();
}

__global__ __launch_bounds__(256, 2) void loop_gemm_kernel(MP x, size_t xoff,
                                                           const float* __restrict__ wp,
                                                           float* __restrict__ agg,
                                                           const int* __restrict__ flagp) {
  __shared__ float As[TE][LDA];
  __shared__ float Bs[KK][DIM];
  const int bf = *flagp;
  const int tid = threadIdx.x;
  const int m0 = blockIdx.x * TE;
  for (int i = tid; i < TE * (DIM / 8); i += 256) {
    int r = i / (DIM / 8), c8 = i - r * (DIM / 8);
    float o[8];
    ld8(x, xoff + (size_t)(m0 + r) * DIM + c8 * 8, o, bf);
    float4* d = (float4*)&As[r][c8 * 8];
    d[0] = make_float4(o[0], o[1], o[2], o[3]);
    d[1] = make_float4(o[4], o[5], o[6], o[7]);
  }
  const int rg = tid >> 3, cg = tid & 7;
  const int r0 = rg * 2, c0 = cg * 25;
  float acc0[25], acc1[25];
#pragma unroll
  for (int j = 0; j < 25; ++j) { acc0[j] = 0.f; acc1[j] = 0.f; }
  MP wpm; wpm.p = wp;
  gemm_tile(As, Bs, wpm, 0, r0, c0, acc0, acc1, tid);
  float* o0 = agg + (size_t)(m0 + r0) * DIM + c0;
  float* o1 = agg + (size_t)(m0 + r0 + 1) * DIM + c0;
#pragma unroll
  for (int j = 0; j < 25; ++j) { o0[j] = acc0[j]; o1[j] = acc1[j]; }
}

__global__ __launch_bounds__(256, 2) void edge_kernel(
    MP x, size_t xoff, const float* __restrict__ re,
    const int* __restrict__ ei, const int* __restrict__ ety,
    const int* __restrict__ qe, const int* __restrict__ qr,
    const float* __restrict__ normA,
    MP w_q, MP w_in, MP w_out,
    float* __restrict__ agg, const int* __restrict__ flagp) {
  __shared__ float As[TE][LDA];
  __shared__ float Bs[KK][DIM];
  __shared__ int s_src[TE], s_dst[TE], s_et[TE];
  __shared__ int s_qe0[TE], s_qe1[TE], s_qr0[TE], s_qr1[TE];
  __shared__ float s_norm[TE];

  const int bf = *flagp;
  const int tid = threadIdx.x;
  const int blk = blockIdx.x;
  const int side = blk >= NTS ? 1 : 0;
  const int eb = (blk - side * NTS) * TE;
  const int gb = side * EE + eb;

  if (tid < TE) {
    int ge = gb + tid;
    s_src[tid] = ei[ge];
    s_dst[tid] = ei[TOTE + ge];
    s_et[tid]  = ety[ge];
    s_qe0[tid] = qe[ge];
    s_qe1[tid] = qe[TOTE + ge];
    s_qr0[tid] = qr[ge];
    s_qr1[tid] = qr[TOTE + ge];
    s_norm[tid] = normA[ge];
  }
  __syncthreads();

  for (int i = tid; i < TE * (DIM / 8); i += 256) {
    int r = i / (DIM / 8), c8 = i - r * (DIM / 8);
    float xa[8], ra[8], xb[8], rb[8], o[8];
    ld8(x, xoff + (size_t)s_qe0[r] * DIM + c8 * 8, xa, bf);
    f32load8(re + (size_t)s_qr0[r] * DIM + c8 * 8, ra);
    ld8(x, xoff + (size_t)s_qe1[r] * DIM + c8 * 8, xb, bf);
    f32load8(re + (size_t)s_qr1[r] * DIM + c8 * 8, rb);
#pragma unroll
    for (int j = 0; j < 8; ++j) o[j] = xa[j] * ra[j] + xb[j] * rb[j];
    float4* d = (float4*)&As[r][c8 * 8];
    d[0] = make_float4(o[0], o[1], o[2], o[3]);
    d[1] = make_float4(o[4], o[5], o[6], o[7]);
  }

  const int rg = tid >> 3, cg = tid & 7;
  const int r0 = rg * 2, c0 = cg * 25;
  float acc0[25], acc1[25];
#pragma unroll
  for (int j = 0; j < 25; ++j) { acc0[j] = 0.f; acc1[j] = 0.f; }

  gemm_tile(As, Bs, w_q, bf, r0, c0, acc0, acc1, tid);

  {
    const size_t e0 = (size_t)s_et[r0] * DIM, e1 = (size_t)s_et[r0 + 1] * DIM;
    const size_t sx0 = xoff + (size_t)s_src[r0] * DIM, sx1 = xoff + (size_t)s_src[r0 + 1] * DIM;
#pragma unroll
    for (int j = 0; j < 25; ++j) {
      int c = c0 + j;
      float q0 = 0.5f * (re[e0 + c] + acc0[j]);
      float q1 = 0.5f * (re[e1 + c] + acc1[j]);
      As[r0][c]     = ld(x, sx0 + c, bf) * q0;
      As[r0 + 1][c] = ld(x, sx1 + c, bf) * q1;
      acc0[j] = 0.f; acc1[j] = 0.f;
    }
  }

  gemm_tile(As, Bs, side ? w_out : w_in, bf, r0, c0, acc0, acc1, tid);

  {
    const float n0 = s_norm[r0], n1 = s_norm[r0 + 1];
    float* a0p = agg + (size_t)s_dst[r0] * DIM + c0;
    float* a1p = agg + (size_t)s_dst[r0 + 1] * DIM + c0;
#pragma unroll
    for (int j = 0; j < 25; ++j) {
      atomicAdd(a0p + j, acc0[j] * n0);
      atomicAdd(a1p + j, acc1[j] * n1);
    }
  }
}

// ---------------- BatchNorm + gather ----------------
__global__ __launch_bounds__(256) void bn_reduce_kernel(const float* __restrict__ agg,
                                                        float* __restrict__ sums) {
  int tid = threadIdx.x;
  if (tid >= DIM) return;
  int row0 = blockIdx.x * 160;
  float s = 0.f, s2 = 0.f;
  for (int r = row0; r < row0 + 160; ++r) {
    float v = agg[(size_t)r * DIM + tid] * (1.f / 3.f);
    s += v; s2 += v * v;
  }
  atomicAdd(&sums[tid], s);
  atomicAdd(&sums[DIM + tid], s2);
}

__global__ __launch_bounds__(256) void bn_apply_kernel(const float* __restrict__ agg,
                                                       const float* __restrict__ sums,
                                                       MP gamma, MP beta,
                                                       void* __restrict__ xout, size_t ooff,
                                                       const int* __restrict__ flagp) {
  __shared__ float sc[DIM], sh[DIM];
  const int bf = *flagp;
  int tid = threadIdx.x;
  if (tid < DIM) {
    float mean = sums[tid] * (1.f / NENT);
    float var  = sums[DIM + tid] * (1.f / NENT) - mean * mean;
    float s = ld(gamma, tid, bf) * rsqrtf(var + EPSBN);
    sc[tid] = s;
    sh[tid] = ld(beta, tid, bf) - mean * s;
  }
  __syncthreads();
  int stride = gridDim.x * blockDim.x;
  for (int i = blockIdx.x * blockDim.x + tid; i < NENT * DIM; i += stride) {
    int c = i % DIM;
    float v = agg[i] * (1.f / 3.f);
    st(xout, ooff + i, tanhf(fmaf(v, sc[c], sh[c])), bf);
  }
}

__global__ void gather_kernel(void* __restrict__ out, const float* __restrict__ rfin,
                              const int* __restrict__ sub, const int* __restrict__ rel,
                              const int* __restrict__ flagp) {
  const int bf = *flagp;
  int i = blockIdx.x * 256 + threadIdx.x;
  MP xm; xm.p = out;
  if (i < BQ * DIM) {
    int b = i / DIM, c = i - b * DIM;
    st(out, i, ld(xm, XOFF + (size_t)sub[b] * DIM + c, bf), bf);
  } else if (i < 2 * BQ * DIM) {
    int j = i - BQ * DIM;
    int b = j / DIM, c = j - b * DIM;
    st(out, i, rfin[(size_t)rel[b] * DIM + c], bf);
  }
}

// ---------------- launch ----------------
extern "C" void kernel_launch(void* const* d_in, const int* in_sizes, int n_in,
                              void* d_out, int out_size, void* d_ws, size_t ws_size,
                              hipStream_t stream) {
  (void)in_sizes; (void)n_in; (void)out_size;
  const int* ei  = (const int*)d_in[0];
  const int* ety = (const int*)d_in[1];
  const int* qe  = (const int*)d_in[2];
  const int* qr  = (const int*)d_in[3];
  const int* sub = (const int*)d_in[4];
  const int* rel = (const int*)d_in[5];
  MP x0 = { d_in[6] };
  MP ir = { d_in[7] };
  MP w_loop[2] = { { d_in[8] },  { d_in[17] } };
  MP w_in[2]   = { { d_in[9] },  { d_in[18] } };
  MP w_out[2]  = { { d_in[10] }, { d_in[19] } };
  MP w_rel[2]  = { { d_in[11] }, { d_in[20] } };
  MP w_q[2]    = { { d_in[12] }, { d_in[21] } };
  MP lr[2]     = { { d_in[13] }, { d_in[22] } };
  MP gamma[2]  = { { d_in[15] }, { d_in[24] } };
  MP beta[2]   = { { d_in[16] }, { d_in[25] } };

  float* ws = (float*)d_ws;
  float* deg_in   = ws;                         // 40000
  float* deg_out  = ws + 40000;                 // 40000
  float* sums1    = ws + 80000;                 // 400
  float* sums2    = ws + 80400;                 // 400
  int*   flag     = (int*)(ws + 80800);         // 16
  float* normA    = ws + 80816;                 // 160000 (in | out)
  float* rel1     = ws + 240816;                // [200,200] f32
  float* rel2     = ws + 280816;
  float* rfin     = ws + 320816;
  float* wp1      = ws + 360816;                // fallback only
  float* wp2      = ws + 400816;                // fallback only
  unsigned short* bt = (unsigned short*)(ws + 440816);      // 8 x [208][224] bf16
  unsigned short* mbf = (unsigned short*)(ws + 627184);     // [160000][224] bf16
  float* agg_fast = ws + 18547184;              // [40000][200] f32
  float* agg_fb   = ws + 440816;                // fallback agg (reuses bt/mbf space)
  const size_t need_fast = 26547184ull * 4ull;  // ~106.2 MB

  const bool fast = ws_size >= need_fast;
  float* agg = fast ? agg_fast : agg_fb;

  hipMemsetAsync(ws, 0, 80800 * sizeof(float), stream);  // deg + sums

  detect_kernel<<<1, 64, 0, stream>>>((const unsigned short*)d_in[6], flag);
  deg_hist_kernel<<<(TOTE + 255) / 256, 256, 0, stream>>>(ei, deg_in, deg_out);
  norm_kernel<<<(TOTE + 255) / 256, 256, 0, stream>>>(ei, deg_in, deg_out, normA);
  copy_f32_kernel<<<(DIM * DIM + 255) / 256, 256, 0, stream>>>(ir, rel1, DIM * DIM, flag);
  mat200_kernel<<<DIM, 256, 0, stream>>>(ir, 1, w_rel[0], rel2, flag);
  MP rel2m = { rel2 };
  mat200_kernel<<<DIM, 256, 0, stream>>>(rel2m, 0, w_rel[1], rfin, flag);

  MP x1 = { d_out };
  if (fast) {
    // Bt: [0]=wq1 [1]=win1 [2]=wout1 [3]=wp1 [4]=wq2 [5]=win2 [6]=wout2 [7]=wp2
    MP nullmp = { nullptr };
    btprep_kernel<<<NP, 256, 0, stream>>>(w_q[0],   nullmp, 0, bt + 0ull * NP * KP, flag);
    btprep_kernel<<<NP, 256, 0, stream>>>(w_in[0],  nullmp, 0, bt + 1ull * NP * KP, flag);
    btprep_kernel<<<NP, 256, 0, stream>>>(w_out[0], nullmp, 0, bt + 2ull * NP * KP, flag);
    btprep_kernel<<<NP, 256, 0, stream>>>(w_loop[0], lr[0], 1, bt + 3ull * NP * KP, flag);
    btprep_kernel<<<NP, 256, 0, stream>>>(w_q[1],   nullmp, 0, bt + 4ull * NP * KP, flag);
    btprep_kernel<<<NP, 256, 0, stream>>>(w_in[1],  nullmp, 0, bt + 5ull * NP * KP, flag);
    btprep_kernel<<<NP, 256, 0, stream>>>(w_out[1], nullmp, 0, bt + 6ull * NP * KP, flag);
    btprep_kernel<<<NP, 256, 0, stream>>>(w_loop[1], lr[1], 1, bt + 7ull * NP * KP, flag);

    // ---- layer 1 ----
    mfma_gemm<1><<<MT_EDGE, 256, 0, stream>>>(nullptr, x0, 0, rel1, ei, ety, qe, qr, normA,
                                              bt + 0ull * NP * KP, nullptr, agg, mbf, flag);
    mfma_gemm<0><<<MT_LOOP, 256, 0, stream>>>(nullptr, x0, 0, nullptr, nullptr, nullptr,
                                              nullptr, nullptr, nullptr,
                                              bt + 3ull * NP * KP, nullptr, agg, nullptr, flag);
    mfma_gemm<2><<<MT_EDGE, 256, 0, stream>>>(mbf, x0, 0, nullptr, ei, nullptr, nullptr, nullptr,
                                              normA, bt + 1ull * NP * KP, bt + 2ull * NP * KP,
                                              agg, nullptr, flag);
    bn_reduce_kernel<<<NENT / 160, 256, 0, stream>>>(agg, sums1);
    bn_apply_kernel<<<2048, 256, 0, stream>>>(agg, sums1, gamma[0], beta[0], d_out, XOFF, flag);

    // ---- layer 2 ----
    mfma_gemm<1><<<MT_EDGE, 256, 0, stream>>>(nullptr, x1, XOFF, rel2, ei, ety, qe, qr, normA,
                                              bt + 4ull * NP * KP, nullptr, agg, mbf, flag);
    mfma_gemm<0><<<MT_LOOP, 256, 0, stream>>>(nullptr, x1, XOFF, nullptr, nullptr, nullptr,
                                              nullptr, nullptr, nullptr,
                                              bt + 7ull * NP * KP, nullptr, agg, nullptr, flag);
    mfma_gemm<2><<<MT_EDGE, 256, 0, stream>>>(mbf, x1, XOFF, nullptr, ei, nullptr, nullptr,
                                              nullptr, normA, bt + 5ull * NP * KP,
                                              bt + 6ull * NP * KP, agg, nullptr, flag);
    bn_reduce_kernel<<<NENT / 160, 256, 0, stream>>>(agg, sums2);
    bn_apply_kernel<<<2048, 256, 0, stream>>>(agg, sums2, gamma[1], beta[1], d_out, XOFF, flag);
  } else {
    wprime_kernel<<<(DIM * DIM + 255) / 256, 256, 0, stream>>>(w_loop[0], lr[0], wp1, flag);
    wprime_kernel<<<(DIM * DIM + 255) / 256, 256, 0, stream>>>(w_loop[1], lr[1], wp2, flag);

    loop_gemm_kernel<<<NENT / TE, 256, 0, stream>>>(x0, 0, wp1, agg, flag);
    edge_kernel<<<2 * NTS, 256, 0, stream>>>(x0, 0, rel1, ei, ety, qe, qr, normA,
                                             w_q[0], w_in[0], w_out[0], agg, flag);
    bn_reduce_kernel<<<NENT / 160, 256, 0, stream>>>(agg, sums1);
    bn_apply_kernel<<<2048, 256, 0, stream>>>(agg, sums1, gamma[0], beta[0], d_out, XOFF, flag);

    loop_gemm_kernel<<<NENT / TE, 256, 0, stream>>>(x1, XOFF, wp2, agg, flag);
    edge_kernel<<<2 * NTS, 256, 0, stream>>>(x1, XOFF, rel2, ei, ety, qe, qr, normA,
                                             w_q[1], w_in[1], w_out[1], agg, flag);
    bn_reduce_kernel<<<NENT / 160, 256, 0, stream>>>(agg, sums2);
    bn_apply_kernel<<<2048, 256, 0, stream>>>(agg, sums2, gamma[1], beta[1], d_out, XOFF, flag);
  }

  gather_kernel<<<(2 * BQ * DIM + 255) / 256, 256, 0, stream>>>(d_out, rfin, sub, rel, flag);
}

// Round 4
// 1004.279 us; speedup vs baseline: 4.2240x; 1.0663x over previous
//
#include <hip/hip_runtime.h>
#include <hip/hip_bf16.h>
#include <math.h>

using bf16 = __hip_bfloat16;

#define DEV static __device__ __forceinline__

constexpr int NENT = 40000;
constexpr int DIM  = 200;
constexpr int EE   = 80000;      // edges per side
constexpr int TOTE = 2 * EE;     // 160000
constexpr int BQ   = 1024;
constexpr float EPSBN = 1e-5f;
constexpr size_t XOFF = (size_t)2 * BQ * DIM;   // x-region element offset inside d_out

// MFMA geometry: N padded to 208 (13x16), K padded to 224 (7x32)
constexpr int KP   = 224;
constexpr int NP   = 208;
constexpr int LDAS = 232;        // LDS A stride (ushorts): 464B rows -> 2-way-max bank aliasing
constexpr int MT_LOOP = (NENT + 127) / 128;  // 313 (loop kernel M=128)
constexpr int MT_EDGE64 = TOTE / 64;         // 2500 (fused edge kernel M=64)

typedef __attribute__((ext_vector_type(8))) short s8v;   // 8 x bf16 (4 VGPRs)
typedef __attribute__((ext_vector_type(4))) float f4v;   // MFMA accumulator

struct MP { const void* p; };    // world-dtype (bf16|f32) pointer, runtime flag

DEV float b2f(unsigned int u) { union { unsigned int i; float f; } v; v.i = u << 16; return v.f; }

DEV float ld(MP m, size_t i, int bf) {
  return bf ? b2f(((const unsigned short*)m.p)[i]) : ((const float*)m.p)[i];
}
DEV void ld8(MP m, size_t i, float* o, int bf) {
  if (bf) {
    uint4 u = *(const uint4*)((const unsigned short*)m.p + i);
    o[0]=b2f(u.x & 0xffffu); o[1]=b2f(u.x >> 16);
    o[2]=b2f(u.y & 0xffffu); o[3]=b2f(u.y >> 16);
    o[4]=b2f(u.z & 0xffffu); o[5]=b2f(u.z >> 16);
    o[6]=b2f(u.w & 0xffffu); o[7]=b2f(u.w >> 16);
  } else {
    const float4* q = (const float4*)((const float*)m.p + i);
    float4 a = q[0], b = q[1];
    o[0]=a.x; o[1]=a.y; o[2]=a.z; o[3]=a.w; o[4]=b.x; o[5]=b.y; o[6]=b.z; o[7]=b.w;
  }
}
DEV void f32load8(const float* p, float* o) {
  const float4* q = (const float4*)p;
  float4 a = q[0], b = q[1];
  o[0]=a.x; o[1]=a.y; o[2]=a.z; o[3]=a.w; o[4]=b.x; o[5]=b.y; o[6]=b.z; o[7]=b.w;
}
DEV void st(void* p, size_t i, float v, int bf) {
  if (bf) ((bf16*)p)[i] = __float2bfloat16(v);
  else    ((float*)p)[i] = v;
}
DEV unsigned short f2b(float f) {   // RNE f32 -> bf16 bits (inputs never NaN)
  union { float f; unsigned int i; } v; v.f = f;
  return (unsigned short)((v.i + 0x7fffu + ((v.i >> 16) & 1u)) >> 16);
}
DEV uint4 pack8(const float* o) {
  uint4 u;
  u.x = (unsigned)f2b(o[0]) | ((unsigned)f2b(o[1]) << 16);
  u.y = (unsigned)f2b(o[2]) | ((unsigned)f2b(o[3]) << 16);
  u.z = (unsigned)f2b(o[4]) | ((unsigned)f2b(o[5]) << 16);
  u.w = (unsigned)f2b(o[6]) | ((unsigned)f2b(o[7]) << 16);
  return u;
}

// ---------------- dtype detect ----------------
__global__ void detect_kernel(const unsigned short* __restrict__ e, int* __restrict__ flag) {
  int tid = threadIdx.x;
  int absurd = 0;
  for (int i = tid; i < 2048; i += 64) {
    int ex = (e[i] >> 7) & 0xFF;
    if (ex >= 0xD0 || (ex != 0 && ex <= 0x50)) absurd++;
  }
  for (int o = 32; o; o >>= 1) absurd += __shfl_down(absurd, o);
  if (tid == 0) *flag = (absurd > 64) ? 0 : 1;   // 1 => bf16 world
}

// ---------------- small kernels ----------------
__global__ void deg_hist_kernel(const int* __restrict__ ei,
                                float* __restrict__ deg_in, float* __restrict__ deg_out) {
  int i = blockIdx.x * 256 + threadIdx.x;
  if (i >= TOTE) return;
  atomicAdd((i < EE ? deg_in : deg_out) + ei[i], 1.0f);
}

__global__ void norm_kernel(const int* __restrict__ ei,
                            const float* __restrict__ deg_in, const float* __restrict__ deg_out,
                            float* __restrict__ normA) {
  int i = blockIdx.x * 256 + threadIdx.x;
  if (i >= TOTE) return;
  int s = ei[i], d = ei[TOTE + i];
  const float* deg = (i < EE) ? deg_in : deg_out;
  float a = deg[s], b = deg[d];
  float na = a > 0.f ? rsqrtf(a) : 0.f;
  float nb = b > 0.f ? rsqrtf(b) : 0.f;
  normA[i] = na * nb;
}

__global__ void copy_f32_kernel(MP s, float* __restrict__ d, int n, const int* __restrict__ flagp) {
  int bf = *flagp;
  int i = blockIdx.x * 256 + threadIdx.x;
  if (i < n) d[i] = ld(s, i, bf);
}

__global__ void mat200_kernel(MP A, int a_use_flag, MP B, float* __restrict__ C,
                              const int* __restrict__ flagp) {
  int bf = *flagp;
  int abf = a_use_flag ? bf : 0;
  int i = blockIdx.x, c = threadIdx.x;
  if (c >= DIM) return;
  float acc = 0.f;
  for (int d = 0; d < DIM; ++d)
    acc = fmaf(ld(A, (size_t)i * DIM + d, abf), ld(B, (size_t)d * DIM + c, bf), acc);
  C[(size_t)i * DIM + c] = acc;
}

// Bt[n][k] = W^T padded to [208][224] bf16, optionally folding loop_rel
__global__ void btprep_kernel(MP w, MP lrp, int has_lr, unsigned short* __restrict__ bt,
                              const int* __restrict__ flagp) {
  int bf = *flagp;
  int n = blockIdx.x, k = threadIdx.x;
  if (k >= KP) return;
  float v = 0.f;
  if (n < DIM && k < DIM) {
    v = ld(w, (size_t)k * DIM + n, bf);
    if (has_lr) v *= ld(lrp, k, bf);
  }
  bt[(size_t)n * KP + k] = f2b(v);
}

// ---------------- loop (self-edge) MFMA GEMM: agg = x @ wp'  (M=128, plain store) ----------------
__global__ __launch_bounds__(256, 2) void loop_mfma(
    MP x, size_t xoff, const unsigned short* __restrict__ Bt,
    float* __restrict__ agg, const int* __restrict__ flagp) {
  __shared__ unsigned short As[128][LDAS];
  const int bf  = *flagp;
  const int tid = threadIdx.x;
  const int m0  = blockIdx.x * 128;

  for (int i = tid; i < 128 * 28; i += 256) {
    int r = i / 28, cg = i - r * 28;
    float o[8] = {0,0,0,0,0,0,0,0};
    int row = m0 + r;
    if (row < NENT && cg < 25) ld8(x, xoff + (size_t)row * DIM + cg * 8, o, bf);
    *(uint4*)&As[r][cg * 8] = pack8(o);
  }
  __syncthreads();

  const int lane = tid & 63;
  const int w    = tid >> 6;
  const int col  = lane & 15;
  const int quad = lane >> 4;
  const unsigned short* btl = Bt + (size_t)col * KP + quad * 8;

  f4v acc[26];
#pragma unroll
  for (int t = 0; t < 26; ++t) acc[t] = (f4v){0.f, 0.f, 0.f, 0.f};

  const int rbase = w * 32;
#pragma unroll
  for (int kc = 0; kc < 7; ++kc) {
    const int k0 = kc * 32;
    s8v a0 = __builtin_bit_cast(s8v, *(const uint4*)&As[rbase + col][k0 + quad * 8]);
    s8v a1 = __builtin_bit_cast(s8v, *(const uint4*)&As[rbase + 16 + col][k0 + quad * 8]);
#pragma unroll
    for (int nt = 0; nt < 13; ++nt) {
      s8v b = __builtin_bit_cast(s8v, *(const uint4*)(btl + (size_t)nt * 16 * KP + k0));
      acc[nt]      = __builtin_amdgcn_mfma_f32_16x16x32_bf16(a0, b, acc[nt], 0, 0, 0);
      acc[13 + nt] = __builtin_amdgcn_mfma_f32_16x16x32_bf16(a1, b, acc[13 + nt], 0, 0, 0);
    }
  }

#pragma unroll
  for (int mt = 0; mt < 2; ++mt) {
#pragma unroll
    for (int i = 0; i < 4; ++i) {
      const int grow = m0 + rbase + mt * 16 + quad * 4 + i;
      if (grow < NENT) {
        float* ap = agg + (size_t)grow * DIM;
#pragma unroll
        for (int nt = 0; nt < 13; ++nt) {
          int n = nt * 16 + col;
          if (n < DIM) ap[n] = acc[mt * 13 + nt][i];
        }
      }
    }
  }
}

// ---------------- fused edge kernel: qual GEMM -> rel_e -> m (LDS C->A) -> msg GEMM -> atomic scatter ----
// M=64 tile, 1 m-tile/wave: each wave reads/rewrites ONLY As rows [16w,16w+16) after staging,
// so the C->A transpose through LDS needs no extra barriers (wave-private rows).
__global__ __launch_bounds__(256, 4) void edge_fused(
    MP x, size_t xoff, const float* __restrict__ re,
    const int* __restrict__ ei, const int* __restrict__ ety,
    const int* __restrict__ qe, const int* __restrict__ qr,
    const float* __restrict__ normA,
    const unsigned short* __restrict__ BtQ,
    const unsigned short* __restrict__ BtIn, const unsigned short* __restrict__ BtOut,
    float* __restrict__ agg, const int* __restrict__ flagp) {
  __shared__ unsigned short As[64][LDAS];           // 29.7 KB
  __shared__ int sQe0[64], sQe1[64], sQr0[64], sQr1[64], sSrc[64], sEty[64], sDst[64];
  __shared__ float sN[64];

  const int bf  = *flagp;
  const int tid = threadIdx.x;
  const int m0  = blockIdx.x * 64;
  const int side = (m0 >= EE) ? 1 : 0;

  if (tid < 64) {
    int e = m0 + tid;
    sQe0[tid] = qe[e];        sQe1[tid] = qe[TOTE + e];
    sQr0[tid] = qr[e];        sQr1[tid] = qr[TOTE + e];
    sSrc[tid] = ei[e];        sEty[tid] = ety[e];
    sDst[tid] = ei[TOTE + e]; sN[tid]   = normA[e];
  }
  __syncthreads();

  // stage t1 = sum_q x[qe]*re[qr] into As (64 x 224 bf16), pad cols zeroed
  for (int i = tid; i < 64 * 28; i += 256) {
    int r = i / 28, cg = i - r * 28;
    float o[8] = {0,0,0,0,0,0,0,0};
    if (cg < 25) {
      float xa[8], ra[8], xb[8], rb[8];
      ld8(x, xoff + (size_t)sQe0[r] * DIM + cg * 8, xa, bf);
      f32load8(re + (size_t)sQr0[r] * DIM + cg * 8, ra);
      ld8(x, xoff + (size_t)sQe1[r] * DIM + cg * 8, xb, bf);
      f32load8(re + (size_t)sQr1[r] * DIM + cg * 8, rb);
#pragma unroll
      for (int j = 0; j < 8; ++j) o[j] = xa[j] * ra[j] + xb[j] * rb[j];
    }
    *(uint4*)&As[r][cg * 8] = pack8(o);
  }
  __syncthreads();
  // ---- from here on, wave w touches only As rows [16w, 16w+16) ----

  const int lane = tid & 63;
  const int w    = tid >> 6;
  const int col  = lane & 15;
  const int quad = lane >> 4;
  const int rbase = w * 16;

  f4v acc[13];
#pragma unroll
  for (int t = 0; t < 13; ++t) acc[t] = (f4v){0.f, 0.f, 0.f, 0.f};

  // GEMM 1: qual = t1 @ w_q^T
  {
    const unsigned short* btl = BtQ + (size_t)col * KP + quad * 8;
#pragma unroll
    for (int kc = 0; kc < 7; ++kc) {
      const int k0 = kc * 32;
      s8v a = __builtin_bit_cast(s8v, *(const uint4*)&As[rbase + col][k0 + quad * 8]);
#pragma unroll
      for (int nt = 0; nt < 13; ++nt) {
        s8v b = __builtin_bit_cast(s8v, *(const uint4*)(btl + (size_t)nt * 16 * KP + k0));
        acc[nt] = __builtin_amdgcn_mfma_f32_16x16x32_bf16(a, b, acc[nt], 0, 0, 0);
      }
    }
  }

  // epilogue 1: m = x[src] * 0.5*(re[ety] + qual) -> back into own As rows (C->A transpose)
#pragma unroll
  for (int i = 0; i < 4; ++i) {
    const int lrow = rbase + quad * 4 + i;
    const float* rerow = re + (size_t)sEty[lrow] * DIM;
    const size_t xrow = xoff + (size_t)sSrc[lrow] * DIM;
#pragma unroll
    for (int nt = 0; nt < 13; ++nt) {
      int n = nt * 16 + col;
      float v = 0.f;
      if (n < DIM) v = ld(x, xrow + n, bf) * (0.5f * (rerow[n] + acc[nt][i]));
      if (n < NP) As[lrow][n] = f2b(v);
    }
    As[lrow][NP + col] = 0;    // zero k-pad cols 208..223
  }

#pragma unroll
  for (int t = 0; t < 13; ++t) acc[t] = (f4v){0.f, 0.f, 0.f, 0.f};

  // GEMM 2: msg = m @ (w_in|w_out)^T   (same wave-private As rows; lgkmcnt orders write->read)
  {
    const unsigned short* btl = (side ? BtOut : BtIn) + (size_t)col * KP + quad * 8;
#pragma unroll
    for (int kc = 0; kc < 7; ++kc) {
      const int k0 = kc * 32;
      s8v a = __builtin_bit_cast(s8v, *(const uint4*)&As[rbase + col][k0 + quad * 8]);
#pragma unroll
      for (int nt = 0; nt < 13; ++nt) {
        s8v b = __builtin_bit_cast(s8v, *(const uint4*)(btl + (size_t)nt * 16 * KP + k0));
        acc[nt] = __builtin_amdgcn_mfma_f32_16x16x32_bf16(a, b, acc[nt], 0, 0, 0);
      }
    }
  }

  // epilogue 2: agg[dst] += msg * norm
#pragma unroll
  for (int i = 0; i < 4; ++i) {
    const int lrow = rbase + quad * 4 + i;
    const float nv = sN[lrow];
    float* ap = agg + (size_t)sDst[lrow] * DIM;
#pragma unroll
    for (int nt = 0; nt < 13; ++nt) {
      int n = nt * 16 + col;
      if (n < DIM) atomicAdd(ap + n, acc[nt][i] * nv);
    }
  }
}

// ---------------- BatchNorm + gather ----------------
__global__ __launch_bounds__(256) void bn_reduce_kernel(const float* __restrict__ agg,
                                                        float* __restrict__ sums) {
  int tid = threadIdx.x;
  if (tid >= DIM) return;
  int row0 = blockIdx.x * 160;
  float s = 0.f, s2 = 0.f;
  for (int r = row0; r < row0 + 160; ++r) {
    float v = agg[(size_t)r * DIM + tid] * (1.f / 3.f);
    s += v; s2 += v * v;
  }
  atomicAdd(&sums[tid], s);
  atomicAdd(&sums[DIM + tid], s2);
}

__global__ __launch_bounds__(256) void bn_apply_kernel(const float* __restrict__ agg,
                                                       const float* __restrict__ sums,
                                                       MP gamma, MP beta,
                                                       void* __restrict__ xout, size_t ooff,
                                                       const int* __restrict__ flagp) {
  __shared__ float sc[DIM], sh[DIM];
  const int bf = *flagp;
  int tid = threadIdx.x;
  if (tid < DIM) {
    float mean = sums[tid] * (1.f / NENT);
    float var  = sums[DIM + tid] * (1.f / NENT) - mean * mean;
    float s = ld(gamma, tid, bf) * rsqrtf(var + EPSBN);
    sc[tid] = s;
    sh[tid] = ld(beta, tid, bf) - mean * s;
  }
  __syncthreads();
  int stride = gridDim.x * blockDim.x;
  for (int i = blockIdx.x * blockDim.x + tid; i < NENT * DIM; i += stride) {
    int c = i % DIM;
    float v = agg[i] * (1.f / 3.f);
    st(xout, ooff + i, tanhf(fmaf(v, sc[c], sh[c])), bf);
  }
}

__global__ void gather_kernel(void* __restrict__ out, const float* __restrict__ rfin,
                              const int* __restrict__ sub, const int* __restrict__ rel,
                              const int* __restrict__ flagp) {
  const int bf = *flagp;
  int i = blockIdx.x * 256 + threadIdx.x;
  MP xm; xm.p = out;
  if (i < BQ * DIM) {
    int b = i / DIM, c = i - b * DIM;
    st(out, i, ld(xm, XOFF + (size_t)sub[b] * DIM + c, bf), bf);
  } else if (i < 2 * BQ * DIM) {
    int j = i - BQ * DIM;
    int b = j / DIM, c = j - b * DIM;
    st(out, i, rfin[(size_t)rel[b] * DIM + c], bf);
  }
}

// ---------------- launch ----------------
extern "C" void kernel_launch(void* const* d_in, const int* in_sizes, int n_in,
                              void* d_out, int out_size, void* d_ws, size_t ws_size,
                              hipStream_t stream) {
  (void)in_sizes; (void)n_in; (void)out_size; (void)ws_size;
  const int* ei  = (const int*)d_in[0];
  const int* ety = (const int*)d_in[1];
  const int* qe  = (const int*)d_in[2];
  const int* qr  = (const int*)d_in[3];
  const int* sub = (const int*)d_in[4];
  const int* rel = (const int*)d_in[5];
  MP x0 = { d_in[6] };
  MP ir = { d_in[7] };
  MP w_loop[2] = { { d_in[8] },  { d_in[17] } };
  MP w_in[2]   = { { d_in[9] },  { d_in[18] } };
  MP w_out[2]  = { { d_in[10] }, { d_in[19] } };
  MP w_rel[2]  = { { d_in[11] }, { d_in[20] } };
  MP w_q[2]    = { { d_in[12] }, { d_in[21] } };
  MP lr[2]     = { { d_in[13] }, { d_in[22] } };
  MP gamma[2]  = { { d_in[15] }, { d_in[24] } };
  MP beta[2]   = { { d_in[16] }, { d_in[25] } };

  float* ws = (float*)d_ws;
  float* deg_in   = ws;                         // 40000
  float* deg_out  = ws + 40000;                 // 40000
  float* sums1    = ws + 80000;                 // 400
  float* sums2    = ws + 80400;                 // 400
  int*   flag     = (int*)(ws + 80800);         // 16
  float* normA    = ws + 80816;                 // 160000
  float* rel1     = ws + 240816;                // [200,200] f32
  float* rel2     = ws + 280816;
  float* rfin     = ws + 320816;
  unsigned short* bt = (unsigned short*)(ws + 440816);  // 8 x [208][224] bf16
  float* agg      = ws + 18547184;              // [40000][200] f32 (offset proven safe in r3)

  hipMemsetAsync(ws, 0, 80800 * sizeof(float), stream);  // deg + sums

  detect_kernel<<<1, 64, 0, stream>>>((const unsigned short*)d_in[6], flag);
  deg_hist_kernel<<<(TOTE + 255) / 256, 256, 0, stream>>>(ei, deg_in, deg_out);
  norm_kernel<<<(TOTE + 255) / 256, 256, 0, stream>>>(ei, deg_in, deg_out, normA);
  copy_f32_kernel<<<(DIM * DIM + 255) / 256, 256, 0, stream>>>(ir, rel1, DIM * DIM, flag);
  mat200_kernel<<<DIM, 256, 0, stream>>>(ir, 1, w_rel[0], rel2, flag);
  MP rel2m = { rel2 };
  mat200_kernel<<<DIM, 256, 0, stream>>>(rel2m, 0, w_rel[1], rfin, flag);

  // Bt: [0]=wq1 [1]=win1 [2]=wout1 [3]=wp1 [4]=wq2 [5]=win2 [6]=wout2 [7]=wp2
  MP nullmp = { nullptr };
  btprep_kernel<<<NP, 256, 0, stream>>>(w_q[0],   nullmp, 0, bt + 0ull * NP * KP, flag);
  btprep_kernel<<<NP, 256, 0, stream>>>(w_in[0],  nullmp, 0, bt + 1ull * NP * KP, flag);
  btprep_kernel<<<NP, 256, 0, stream>>>(w_out[0], nullmp, 0, bt + 2ull * NP * KP, flag);
  btprep_kernel<<<NP, 256, 0, stream>>>(w_loop[0], lr[0], 1, bt + 3ull * NP * KP, flag);
  btprep_kernel<<<NP, 256, 0, stream>>>(w_q[1],   nullmp, 0, bt + 4ull * NP * KP, flag);
  btprep_kernel<<<NP, 256, 0, stream>>>(w_in[1],  nullmp, 0, bt + 5ull * NP * KP, flag);
  btprep_kernel<<<NP, 256, 0, stream>>>(w_out[1], nullmp, 0, bt + 6ull * NP * KP, flag);
  btprep_kernel<<<NP, 256, 0, stream>>>(w_loop[1], lr[1], 1, bt + 7ull * NP * KP, flag);

  MP x1 = { d_out };

  // ---- layer 1 ----
  loop_mfma<<<MT_LOOP, 256, 0, stream>>>(x0, 0, bt + 3ull * NP * KP, agg, flag);
  edge_fused<<<MT_EDGE64, 256, 0, stream>>>(x0, 0, rel1, ei, ety, qe, qr, normA,
                                            bt + 0ull * NP * KP, bt + 1ull * NP * KP,
                                            bt + 2ull * NP * KP, agg, flag);
  bn_reduce_kernel<<<NENT / 160, 256, 0, stream>>>(agg, sums1);
  bn_apply_kernel<<<2048, 256, 0, stream>>>(agg, sums1, gamma[0], beta[0], d_out, XOFF, flag);

  // ---- layer 2 (x1 lives in d_out x-region) ----
  loop_mfma<<<MT_LOOP, 256, 0, stream>>>(x1, XOFF, bt + 7ull * NP * KP, agg, flag);
  edge_fused<<<MT_EDGE64, 256, 0, stream>>>(x1, XOFF, rel2, ei, ety, qe, qr, normA,
                                            bt + 4ull * NP * KP, bt + 5ull * NP * KP,
                                            bt + 6ull * NP * KP, agg, flag);
  bn_reduce_kernel<<<NENT / 160, 256, 0, stream>>>(agg, sums2);
  bn_apply_kernel<<<2048, 256, 0, stream>>>(agg, sums2, gamma[1], beta[1], d_out, XOFF, flag);

  gather_kernel<<<(2 * BQ * DIM + 255) / 256, 256, 0, stream>>>(d_out, rfin, sub, rel, flag);
}